// Round 1
// baseline (965.117 us; speedup 1.0000x reference)
//
#include <hip/hip_runtime.h>
#include <math.h>

// QuadraticNetCholesky: out[b] = L Lᵀ where tril(L) = softplus(MLP(x[b])).
// MLP: 12 -> 128 (ELU) -> 32 (ELU) -> 78 (softplus).
// One thread per sample, fp32 end-to-end. Weights are read with wave-uniform
// addresses from __restrict__ global pointers so the backend can scalarize
// them into s_load + SGPR-operand v_fma (avoids LDS broadcast bandwidth).

namespace {

constexpr int ND  = 12;   // Cholesky dim
constexpr int TRI = 78;   // lower-tri count

__device__ __forceinline__ float elu_f(float x) {
    // jax.nn.elu, alpha=1: x>0 ? x : expm1(x)
    float e = __expf(x) - 1.0f;
    return x > 0.0f ? x : e;
}

__device__ __forceinline__ float softplus_f(float x) {
    // stable log1p(exp(x)) = max(x,0) + log(1 + exp(-|x|))
    float t = __expf(-fabsf(x));
    return fmaxf(x, 0.0f) + __logf(1.0f + t);
}

__global__ __launch_bounds__(256) void qnc_fused(
    const float* __restrict__ x,
    const float* __restrict__ W1,  // [128][12]
    const float* __restrict__ b1,  // [128]
    const float* __restrict__ W2,  // [32][128]
    const float* __restrict__ b2,  // [32]
    const float* __restrict__ W3,  // [78][32]
    const float* __restrict__ b3,  // [78]
    float* __restrict__ out,       // [B][12][12]
    int batch)
{
    const int b = blockIdx.x * blockDim.x + threadIdx.x;
    if (b >= batch) return;

    // ---- load x[12] (48B, 16B-aligned) ----
    const float4* xp = reinterpret_cast<const float4*>(x + (size_t)b * ND);
    const float4 xa = xp[0], xb = xp[1], xc = xp[2];
    const float xv[ND] = {xa.x, xa.y, xa.z, xa.w,
                          xb.x, xb.y, xb.z, xb.w,
                          xc.x, xc.y, xc.z, xc.w};

    // ---- layer1 + layer2 fused, h1 processed in 4 chunks of 32 ----
    float h2[32];
    #pragma unroll
    for (int k = 0; k < 32; ++k) h2[k] = b2[k];

    for (int c = 0; c < 4; ++c) {              // h1 index j = c*32 + jj
        float hc[32];
        #pragma unroll
        for (int jj = 0; jj < 32; ++jj) {
            const float* w = W1 + (c * 32 + jj) * ND;   // uniform addr
            float p0 = b1[c * 32 + jj], p1 = 0.f, p2 = 0.f, p3 = 0.f;
            #pragma unroll
            for (int q = 0; q < 3; ++q) {
                p0 = fmaf(xv[4*q+0], w[4*q+0], p0);
                p1 = fmaf(xv[4*q+1], w[4*q+1], p1);
                p2 = fmaf(xv[4*q+2], w[4*q+2], p2);
                p3 = fmaf(xv[4*q+3], w[4*q+3], p3);
            }
            hc[jj] = elu_f((p0 + p1) + (p2 + p3));
        }
        #pragma unroll
        for (int k = 0; k < 32; ++k) {
            const float* w = W2 + k * 128 + c * 32;     // contiguous row chunk
            float a0 = 0.f, a1 = 0.f, a2 = 0.f, a3 = 0.f;
            #pragma unroll
            for (int q = 0; q < 8; ++q) {
                a0 = fmaf(hc[4*q+0], w[4*q+0], a0);
                a1 = fmaf(hc[4*q+1], w[4*q+1], a1);
                a2 = fmaf(hc[4*q+2], w[4*q+2], a2);
                a3 = fmaf(hc[4*q+3], w[4*q+3], a3);
            }
            h2[k] += (a0 + a1) + (a2 + a3);
        }
    }
    #pragma unroll
    for (int k = 0; k < 32; ++k) h2[k] = elu_f(h2[k]);

    // ---- layer3 + softplus -> lower-tri L[78] (kept in registers) ----
    float L[TRI];
    #pragma unroll
    for (int t = 0; t < TRI; ++t) {
        const float* w = W3 + t * 32;                   // uniform addr
        float a0 = b3[t], a1 = 0.f, a2 = 0.f, a3 = 0.f;
        #pragma unroll
        for (int q = 0; q < 8; ++q) {
            a0 = fmaf(h2[4*q+0], w[4*q+0], a0);
            a1 = fmaf(h2[4*q+1], w[4*q+1], a1);
            a2 = fmaf(h2[4*q+2], w[4*q+2], a2);
            a3 = fmaf(h2[4*q+3], w[4*q+3], a3);
        }
        L[t] = softplus_f((a0 + a1) + (a2 + a3));
    }

    // ---- out = L Lᵀ, row by row; L[i][j] = L[i*(i+1)/2 + j], j<=i ----
    float* ob = out + (size_t)b * (ND * ND);
    #pragma unroll
    for (int i = 0; i < ND; ++i) {
        float r[ND];
        #pragma unroll
        for (int k = 0; k < ND; ++k) {
            const int m = (i < k) ? i : k;
            float s0 = 0.f, s1 = 0.f;
            #pragma unroll
            for (int j = 0; j <= m; ++j) {
                const float p = L[i*(i+1)/2 + j] * L[k*(k+1)/2 + j];
                if (j & 1) s1 += p; else s0 += p;
            }
            r[k] = s0 + s1;
        }
        float4* op = reinterpret_cast<float4*>(ob + i * ND);  // 48B, aligned
        op[0] = make_float4(r[0], r[1], r[2],  r[3]);
        op[1] = make_float4(r[4], r[5], r[6],  r[7]);
        op[2] = make_float4(r[8], r[9], r[10], r[11]);
    }
}

} // namespace

extern "C" void kernel_launch(void* const* d_in, const int* in_sizes, int n_in,
                              void* d_out, int out_size, void* d_ws, size_t ws_size,
                              hipStream_t stream) {
    const float* x  = (const float*)d_in[0];
    const float* W1 = (const float*)d_in[1];
    const float* b1 = (const float*)d_in[2];
    const float* W2 = (const float*)d_in[3];
    const float* b2 = (const float*)d_in[4];
    const float* W3 = (const float*)d_in[5];
    const float* b3 = (const float*)d_in[6];
    float* out = (float*)d_out;

    const int batch  = in_sizes[0] / ND;          // 262144
    const int threads = 256;
    const int blocks  = (batch + threads - 1) / threads;

    qnc_fused<<<blocks, threads, 0, stream>>>(x, W1, b1, W2, b2, W3, b3, out, batch);
}

// Round 2
// 261.254 us; speedup vs baseline: 3.6942x; 3.6942x over previous
//
#include <hip/hip_runtime.h>
#include <math.h>

// QuadraticNetCholesky: out[b] = L Lᵀ, tril(L) = softplus(MLP(x[b])),
// MLP 12 -> 128 (ELU) -> 32 (ELU) -> 78 (softplus).
//
// Round-2 structure:
//  - All weights staged in LDS once per block (33.5 KB); accessed via
//    wave-uniform ds_read_b128 (broadcast) instead of per-lane global loads.
//  - M=2 samples per thread: every weight read amortized over 2 samples.
//    Layers 1+2 fused j-streaming (no hc[32] chunk arrays).
//  - Output coalesced through LDS staging (64 samples x 148-float stride,
//    overlays the dead W1/W2 region in phase B): each global store
//    wave-instruction writes a contiguous 1 KB span. Fixes the 3.6x write
//    amplification seen in round 1 (548 MB vs 151 MB ideal).

namespace {

constexpr int ND  = 12;
constexpr int TRI = 78;
constexpr int BLK = 256;   // threads/block
constexpr int SPB = 512;   // samples/block (M=2)

// LDS layout (float offsets). W3/b3 first (needed in phase B); W1/b1/W2T/b2
// are dead after phase A and get overlaid by the output staging buffer.
constexpr int oW3    = 0;          // 78*32 = 2496
constexpr int oB3    = 2496;       // 78
constexpr int oW1    = 2576;       // 128*12 = 1536   (16B-aligned)
constexpr int oB1    = 4112;       // 128
constexpr int oW2T   = 4240;       // 128*32 = 4096   (transposed W2)
constexpr int oB2    = 8336;       // 32
constexpr int oStage = 2576;       // overlay; 64 samples * STRIDE
constexpr int STRIDE = 148;        // 144 + 4 pad -> full 32-bank coverage for
                                   // lane-strided b128 writes (148 % 32 = 20)
constexpr int LDSF   = oStage + 64 * STRIDE;   // 12048 floats = 48.2 KB

__device__ __forceinline__ float elu_f(float v) {
    return v > 0.0f ? v : __expf(v) - 1.0f;
}
__device__ __forceinline__ float softplus_f(float v) {
    return fmaxf(v, 0.0f) + __logf(1.0f + __expf(-fabsf(v)));
}

__global__ __launch_bounds__(BLK, 2) void qnc(
    const float* __restrict__ x,
    const float* __restrict__ W1, const float* __restrict__ b1,
    const float* __restrict__ W2, const float* __restrict__ b2,
    const float* __restrict__ W3, const float* __restrict__ b3,
    float* __restrict__ out)
{
    __shared__ float lds[LDSF];
    const int t = threadIdx.x;

    // ---- cooperative weight staging (one-time) ----
    for (int i = t; i < 2496; i += BLK) lds[oW3 + i] = W3[i];
    for (int i = t; i < 78;   i += BLK) lds[oB3 + i] = b3[i];
    for (int i = t; i < 1536; i += BLK) lds[oW1 + i] = W1[i];
    for (int i = t; i < 128;  i += BLK) lds[oB1 + i] = b1[i];
    // sW2T[j*32+k] = W2[k*128+j]
    for (int i = t; i < 4096; i += BLK) lds[oW2T + i] = W2[(i & 31) * 128 + (i >> 5)];
    for (int i = t; i < 32;   i += BLK) lds[oB2 + i] = b2[i];
    __syncthreads();

    const long sbase = (long)blockIdx.x * SPB;

    // ---- load x for both samples (3 x b128 each, 48 B stride) ----
    float xv0[ND], xv1[ND];
    {
        const float4* p0 = (const float4*)(x + (sbase + t) * ND);
        const float4* p1 = (const float4*)(x + (sbase + 256 + t) * ND);
        float4 a, b, c;
        a = p0[0]; b = p0[1]; c = p0[2];
        xv0[0]=a.x; xv0[1]=a.y; xv0[2]=a.z; xv0[3]=a.w;
        xv0[4]=b.x; xv0[5]=b.y; xv0[6]=b.z; xv0[7]=b.w;
        xv0[8]=c.x; xv0[9]=c.y; xv0[10]=c.z; xv0[11]=c.w;
        a = p1[0]; b = p1[1]; c = p1[2];
        xv1[0]=a.x; xv1[1]=a.y; xv1[2]=a.z; xv1[3]=a.w;
        xv1[4]=b.x; xv1[5]=b.y; xv1[6]=b.z; xv1[7]=b.w;
        xv1[8]=c.x; xv1[9]=c.y; xv1[10]=c.z; xv1[11]=c.w;
    }

    // ---- phase A: layers 1+2 fused, j-streaming, M=2 ----
    float h20[32], h21[32];
    #pragma unroll
    for (int k = 0; k < 32; ++k) { h20[k] = 0.0f; h21[k] = 0.0f; }

    #pragma unroll 2
    for (int j = 0; j < 128; ++j) {
        const float4 wa = *(const float4*)&lds[oW1 + j*12];
        const float4 wb = *(const float4*)&lds[oW1 + j*12 + 4];
        const float4 wc = *(const float4*)&lds[oW1 + j*12 + 8];
        const float bj = lds[oB1 + j];

        float p0 = fmaf(xv0[0], wa.x, bj);
        float p1 = xv0[1] * wa.y;
        float p2 = xv0[2] * wa.z;
        float p3 = xv0[3] * wa.w;
        p0 = fmaf(xv0[4], wb.x, p0); p1 = fmaf(xv0[5], wb.y, p1);
        p2 = fmaf(xv0[6], wb.z, p2); p3 = fmaf(xv0[7], wb.w, p3);
        p0 = fmaf(xv0[8], wc.x, p0); p1 = fmaf(xv0[9], wc.y, p1);
        p2 = fmaf(xv0[10], wc.z, p2); p3 = fmaf(xv0[11], wc.w, p3);
        const float e0 = elu_f((p0 + p1) + (p2 + p3));

        float q0 = fmaf(xv1[0], wa.x, bj);
        float q1 = xv1[1] * wa.y;
        float q2 = xv1[2] * wa.z;
        float q3 = xv1[3] * wa.w;
        q0 = fmaf(xv1[4], wb.x, q0); q1 = fmaf(xv1[5], wb.y, q1);
        q2 = fmaf(xv1[6], wb.z, q2); q3 = fmaf(xv1[7], wb.w, q3);
        q0 = fmaf(xv1[8], wc.x, q0); q1 = fmaf(xv1[9], wc.y, q1);
        q2 = fmaf(xv1[10], wc.z, q2); q3 = fmaf(xv1[11], wc.w, q3);
        const float e1 = elu_f((q0 + q1) + (q2 + q3));

        const float4* w2r = (const float4*)&lds[oW2T + j*32];
        #pragma unroll
        for (int kk = 0; kk < 8; ++kk) {
            const float4 w = w2r[kk];
            h20[4*kk+0] = fmaf(e0, w.x, h20[4*kk+0]);
            h20[4*kk+1] = fmaf(e0, w.y, h20[4*kk+1]);
            h20[4*kk+2] = fmaf(e0, w.z, h20[4*kk+2]);
            h20[4*kk+3] = fmaf(e0, w.w, h20[4*kk+3]);
            h21[4*kk+0] = fmaf(e1, w.x, h21[4*kk+0]);
            h21[4*kk+1] = fmaf(e1, w.y, h21[4*kk+1]);
            h21[4*kk+2] = fmaf(e1, w.z, h21[4*kk+2]);
            h21[4*kk+3] = fmaf(e1, w.w, h21[4*kk+3]);
        }
    }
    #pragma unroll
    for (int k = 0; k < 32; ++k) {
        const float bk = lds[oB2 + k];
        h20[k] = elu_f(h20[k] + bk);
        h21[k] = elu_f(h21[k] + bk);
    }

    // All threads done reading W1/W2T before the staging overlay reuses them.
    __syncthreads();

    // ---- phase B: layer3 + softplus + L L^T + coalesced write, per m ----
    const int wv = t >> 6, lane = t & 63;
    float* sg = &lds[oStage + lane * STRIDE];

    auto phaseB = [&](const float (&h2)[32], int moff) {
        float L[TRI];
        #pragma unroll
        for (int tt = 0; tt < TRI; ++tt) {
            const float4* w = (const float4*)&lds[oW3 + tt*32];
            float a0 = lds[oB3 + tt], a1 = 0.f, a2 = 0.f, a3 = 0.f;
            #pragma unroll
            for (int q = 0; q < 8; ++q) {
                const float4 wq = w[q];
                a0 = fmaf(h2[4*q+0], wq.x, a0);
                a1 = fmaf(h2[4*q+1], wq.y, a1);
                a2 = fmaf(h2[4*q+2], wq.z, a2);
                a3 = fmaf(h2[4*q+3], wq.w, a3);
            }
            L[tt] = softplus_f((a0 + a1) + (a2 + a3));
        }

        // 4 producer sub-phases: wave p stages its 64 samples (full 576 B
        // contiguous per sample), then all 4 waves write 36 KB coalesced.
        for (int p = 0; p < 4; ++p) {
            if (wv == p) {
                #pragma unroll
                for (int i = 0; i < ND; ++i) {
                    float r[ND];
                    #pragma unroll
                    for (int k = 0; k < ND; ++k) {
                        const int mm = (i < k) ? i : k;
                        float s0 = 0.f, s1 = 0.f;
                        #pragma unroll
                        for (int j2 = 0; j2 <= mm; ++j2) {
                            const float pr = L[i*(i+1)/2 + j2] * L[k*(k+1)/2 + j2];
                            if (j2 & 1) s1 += pr; else s0 += pr;
                        }
                        r[k] = s0 + s1;
                    }
                    float4* sp = (float4*)(sg + i * ND);
                    sp[0] = make_float4(r[0], r[1], r[2],  r[3]);
                    sp[1] = make_float4(r[4], r[5], r[6],  r[7]);
                    sp[2] = make_float4(r[8], r[9], r[10], r[11]);
                }
            }
            __syncthreads();
            float4* g4 = (float4*)(out + (sbase + moff + p * 64) * 144);
            for (int u = t; u < 2304; u += BLK) {          // 9 iters exactly
                const int s = u / 36, q = u - s * 36;
                g4[u] = *(const float4*)&lds[oStage + s * STRIDE + q * 4];
            }
            __syncthreads();
        }
    };

    phaseB(h20, 0);
    phaseB(h21, 256);
}

} // namespace

extern "C" void kernel_launch(void* const* d_in, const int* in_sizes, int n_in,
                              void* d_out, int out_size, void* d_ws, size_t ws_size,
                              hipStream_t stream) {
    const float* x  = (const float*)d_in[0];
    const float* W1 = (const float*)d_in[1];
    const float* b1 = (const float*)d_in[2];
    const float* W2 = (const float*)d_in[3];
    const float* b2 = (const float*)d_in[4];
    const float* W3 = (const float*)d_in[5];
    const float* b3 = (const float*)d_in[6];
    float* out = (float*)d_out;

    const int batch  = in_sizes[0] / ND;      // 262144, divisible by SPB=512
    const int blocks = batch / SPB;           // 512 blocks = 2 per CU

    qnc<<<blocks, BLK, 0, stream>>>(x, W1, b1, W2, b2, W3, b3, out);
}